// Round 8
// baseline (3471.600 us; speedup 1.0000x reference)
//
#include <hip/hip_runtime.h>
#include <cstddef>

// Problem dims (fixed by the reference)
#define Bx 32
#define Sx 2048
#define Hx 256
#define Lx 2

// ------------------------------------------------------------------
// GEMM: C[m,n] = sum_k A[m,k] * W[n,k] + bias[n]   (unchanged; ~185 us,
// becomes a target only after scans drop below ~900 us)
// ------------------------------------------------------------------
#define GBM 64
#define GBN 64
#define GBK 32

__global__ __launch_bounds__(256) void gemm_xp(
    const float* __restrict__ A,
    const float* __restrict__ W,
    const float* __restrict__ bias,
    float* __restrict__ C)
{
    __shared__ float As[GBK][GBM + 1];
    __shared__ float Ws[GBK][GBN + 1];

    const int tid = threadIdx.x;
    const int tx  = tid & 15;
    const int ty  = tid >> 4;
    const int m0  = blockIdx.x * GBM;
    const int n0  = blockIdx.y * GBN;
    const int r   = tid >> 3;
    const int c4  = tid & 7;

    float acc[4][4] = {};

    for (int k0 = 0; k0 < Hx; k0 += GBK) {
        const float4 a0 = *(const float4*)(A + (size_t)(m0 + r)      * Hx + k0 + c4 * 4);
        const float4 a1 = *(const float4*)(A + (size_t)(m0 + r + 32) * Hx + k0 + c4 * 4);
        const float4 w0 = *(const float4*)(W + (size_t)(n0 + r)      * Hx + k0 + c4 * 4);
        const float4 w1 = *(const float4*)(W + (size_t)(n0 + r + 32) * Hx + k0 + c4 * 4);

        __syncthreads();

        As[c4 * 4 + 0][r] = a0.x;  As[c4 * 4 + 1][r] = a0.y;
        As[c4 * 4 + 2][r] = a0.z;  As[c4 * 4 + 3][r] = a0.w;
        As[c4 * 4 + 0][r + 32] = a1.x;  As[c4 * 4 + 1][r + 32] = a1.y;
        As[c4 * 4 + 2][r + 32] = a1.z;  As[c4 * 4 + 3][r + 32] = a1.w;

        Ws[c4 * 4 + 0][r] = w0.x;  Ws[c4 * 4 + 1][r] = w0.y;
        Ws[c4 * 4 + 2][r] = w0.z;  Ws[c4 * 4 + 3][r] = w0.w;
        Ws[c4 * 4 + 0][r + 32] = w1.x;  Ws[c4 * 4 + 1][r + 32] = w1.y;
        Ws[c4 * 4 + 2][r + 32] = w1.z;  Ws[c4 * 4 + 3][r + 32] = w1.w;

        __syncthreads();

        #pragma unroll
        for (int k = 0; k < GBK; ++k) {
            float av[4], wv[4];
            #pragma unroll
            for (int i = 0; i < 4; ++i) av[i] = As[k][ty * 4 + i];
            #pragma unroll
            for (int j = 0; j < 4; ++j) wv[j] = Ws[k][tx * 4 + j];
            #pragma unroll
            for (int i = 0; i < 4; ++i)
                #pragma unroll
                for (int j = 0; j < 4; ++j)
                    acc[i][j] = fmaf(av[i], wv[j], acc[i][j]);
        }
    }

    const float4 bv = *(const float4*)(bias + n0 + tx * 4);
    #pragma unroll
    for (int i = 0; i < 4; ++i) {
        float4 o;
        o.x = acc[i][0] + bv.x;
        o.y = acc[i][1] + bv.y;
        o.z = acc[i][2] + bv.z;
        o.w = acc[i][3] + bv.w;
        *(float4*)(C + (size_t)(m0 + ty * 4 + i) * Hx + n0 + tx * 4) = o;
    }
}

// ------------------------------------------------------------------
// DPP rotate-add: s += lane[(lane+N) mod 16]'s s  (row_ror within 16).
// Four levels (1,2,4,8) give every lane the full 16-lane sum. VALU-only.
//   row_ror:N ctrl = 0x120 | N
// ------------------------------------------------------------------
template <int CTRL>
__device__ __forceinline__ float dpp_xadd(float x) {
    int xi = __builtin_bit_cast(int, x);
    int yi = __builtin_amdgcn_update_dpp(0, xi, CTRL, 0xF, 0xF, true);
    return x + __builtin_bit_cast(float, yi);
}
__device__ __forceinline__ float red16(float s) {
    s = dpp_xadd<0x121>(s);   // + ror 1
    s = dpp_xadd<0x122>(s);   // + ror 2
    s = dpp_xadd<0x124>(s);   // + ror 4
    s = dpp_xadd<0x128>(s);   // + ror 8
    return s;
}

// Opaque register pin ("+v" requires arch VGPRs here). Kept from the
// best-measured round-7 kernel.
__device__ __forceinline__ void pin4(float4 &v) {
    asm volatile("" : "+v"(v.x), "+v"(v.y), "+v"(v.z), "+v"(v.w));
}

// One recurrence step vs the LDS h-buffer at compile-time byte offset
// OFF (0 = buf0, 1024 = buf1). va[] = loop-invariant rotated addresses.
template <int OFF>
__device__ __forceinline__ float step16(const float4 (&wq)[4][4],
                                        const char* const (&va)[4],
                                        float xv, float bias, int lane)
{
    float4 h4[4];
    #pragma unroll
    for (int j = 0; j < 4; ++j)
        h4[j] = *(const float4*)(va[j] + OFF);   // 2-way-aliased (free) ds_read_b128

    float s0 = 0.f, s1 = 0.f, s2 = 0.f, s3 = 0.f;
    #pragma unroll
    for (int j = 0; j < 4; ++j) {
        // component-major: each accumulator's FMAs 4 insts apart (no stalls)
        s0 = fmaf(wq[0][j].x, h4[j].x, s0);
        s1 = fmaf(wq[1][j].x, h4[j].x, s1);
        s2 = fmaf(wq[2][j].x, h4[j].x, s2);
        s3 = fmaf(wq[3][j].x, h4[j].x, s3);
        s0 = fmaf(wq[0][j].y, h4[j].y, s0);
        s1 = fmaf(wq[1][j].y, h4[j].y, s1);
        s2 = fmaf(wq[2][j].y, h4[j].y, s2);
        s3 = fmaf(wq[3][j].y, h4[j].y, s3);
        s0 = fmaf(wq[0][j].z, h4[j].z, s0);
        s1 = fmaf(wq[1][j].z, h4[j].z, s1);
        s2 = fmaf(wq[2][j].z, h4[j].z, s2);
        s3 = fmaf(wq[3][j].z, h4[j].z, s3);
        s0 = fmaf(wq[0][j].w, h4[j].w, s0);
        s1 = fmaf(wq[1][j].w, h4[j].w, s1);
        s2 = fmaf(wq[2][j].w, h4[j].w, s2);
        s3 = fmaf(wq[3][j].w, h4[j].w, s3);
    }

    // 16-lane rotate-reduce on the VALU; every lane gets all 4 sums
    s0 = red16(s0);  s1 = red16(s1);  s2 = red16(s2);  s3 = red16(s3);

    // static select of this lane's output sum (index = lane&3)
    const float sa  = (lane & 1) ? s1 : s0;
    const float sc  = (lane & 1) ? s3 : s2;
    const float sel = (lane & 2) ? sc : sa;

    return tanhf(xv + sel + bias);
}

// ------------------------------------------------------------------
// Recurrence v6: one WG per batch, 1024 threads (16 waves, 4/SIMD),
// 1 barrier/step. Thread t: output-quad g = t>>4 (4 rows), k-slice
// ks = t&15 (16 k each). 64 weight floats/thread (16 float4) — small
// enough for voluntary register residency at the 128-VGPR/4-wave budget.
//
// Round-7 evidence driving this: VALU-issue-bound (87%/active-CU),
// VGPR=88 (128-float weight set refused by RA), serial tail hidden by
// only 2 waves/SIMD. This layout halves per-thread state and doubles
// tail interleave at the same FMA floor (512 cyc/CU/step) and same LDS
// traffic (64KB/step; 4x more threads x 4x less data, broadcast-dedup'd).
// ------------------------------------------------------------------
__global__ __launch_bounds__(1024)
__attribute__((amdgpu_waves_per_eu(4, 4)))
void rnn_scan(
    const float* __restrict__ xp,    // [B,S,H] precomputed x@W_ih^T + b_ih
    const float* __restrict__ h0l,   // [B,H]
    const float* __restrict__ Whh,   // [H,H]
    const float* __restrict__ bhh,   // [H]
    float* __restrict__ y,           // [B,S,H]
    float* __restrict__ hfin)        // [B,H]
{
    const int b    = blockIdx.x;
    const int t    = threadIdx.x;
    const int lane = t & 63;
    const int ks   = lane & 15;                  // k-slice 0..15 (16 floats)
    const int g    = t >> 4;                     // output quad 0..63
    const int out  = g * 4 + (lane & 3);         // output this lane finalizes
    const bool writer = (lane & 12) == 0;        // ks < 4

    // Weights: wq[o][j] = Whh[g*4+o][ks*16 + c*4 .. +3], c = (j+(ks>>2))&3
    // (chunk rotation matches the LDS read rotation below -> 2-way banks).
    float4 wq[4][4];
    #pragma unroll
    for (int o = 0; o < 4; ++o) {
        const float* wrow = Whh + (size_t)(g * 4 + o) * Hx + ks * 16;
        #pragma unroll
        for (int j = 0; j < 4; ++j)
            wq[o][j] = *(const float4*)(wrow + ((j + (ks >> 2)) & 3) * 4);
    }

    __shared__ float hs[2][Hx];                  // buf1 = buf0 + 1024 bytes
    if (t < Hx) hs[0][t] = h0l[(size_t)b * Hx + t];
    const float bias = bhh[out];
    __syncthreads();

    // Loop-invariant rotated LDS addresses (buf0); buf1 via +1024 imm.
    const char* va[4];
    {
        const char* hb0 = (const char*)(&hs[0][0]) + ks * 64;
        #pragma unroll
        for (int j = 0; j < 4; ++j)
            va[j] = hb0 + (((j + (ks >> 2)) & 3) << 4);
    }

    const float* xpb = xp + (size_t)b * Sx * Hx;
    float*       yb  = y  + (size_t)b * Sx * Hx;

    // 2-deep xp prefetch
    float xv_n1 = xpb[out];
    float xv_n2 = xpb[(size_t)Hx + out];
    float hnew  = 0.0f;

    for (int s = 0; s < Sx; s += 2) {
        // Re-pin weights each iteration (16 float4 = 64 regs).
        #pragma unroll
        for (int o = 0; o < 4; ++o)
            #pragma unroll
            for (int j = 0; j < 4; ++j)
                pin4(wq[o][j]);

        // ---- phase 0: read buf0, write buf1 (step s) ----
        {
            const float xv = xv_n1;
            xv_n1 = xv_n2;
            if (s + 2 < Sx) xv_n2 = xpb[(size_t)(s + 2) * Hx + out];

            hnew = step16<0>(wq, va, xv, bias, lane);
            if (writer) {
                hs[1][out] = hnew;
                yb[(size_t)s * Hx + out] = hnew;
            }
            __syncthreads();
        }

        // ---- phase 1: read buf1 (+1024 imm), write buf0 (step s+1) ----
        {
            const float xv = xv_n1;
            xv_n1 = xv_n2;
            if (s + 3 < Sx) xv_n2 = xpb[(size_t)(s + 3) * Hx + out];

            hnew = step16<1024>(wq, va, xv, bias, lane);
            if (writer) {
                hs[0][out] = hnew;
                yb[(size_t)(s + 1) * Hx + out] = hnew;
            }
            __syncthreads();
        }
    }

    if (writer) hfin[(size_t)b * Hx + out] = hnew;
}

// ------------------------------------------------------------------
// Launch: GEMM(l0) -> scan(l0) -> GEMM(l1) -> scan(l1), stream-ordered.
// ws: xp scratch (64 MB). d_out[0:B*S*H] doubles as y1 scratch before the
// layer-2 scan overwrites it (we fully rewrite d_out every call).
// ------------------------------------------------------------------
extern "C" void kernel_launch(void* const* d_in, const int* in_sizes, int n_in,
                              void* d_out, int out_size, void* d_ws, size_t ws_size,
                              hipStream_t stream) {
    const float* x    = (const float*)d_in[0];   // [B,S,H]
    const float* h0   = (const float*)d_in[1];   // [L,B,H]
    const float* W_ih = (const float*)d_in[2];   // [L,H,H]
    const float* W_hh = (const float*)d_in[3];   // [L,H,H]
    const float* b_ih = (const float*)d_in[4];   // [L,H]
    const float* b_hh = (const float*)d_in[5];   // [L,H]

    float* out    = (float*)d_out;                       // [B,S,H]
    float* finals = out + (size_t)Bx * Sx * Hx;          // [L,B,H]
    float* xp     = (float*)d_ws;                        // [B,S,H] scratch

    const dim3 ggrid(Bx * Sx / GBM, Hx / GBN);           // (1024, 4)

    // Layer 0
    gemm_xp<<<ggrid, 256, 0, stream>>>(x, W_ih, b_ih, xp);
    rnn_scan<<<Bx, 1024, 0, stream>>>(xp, h0, W_hh, b_hh,
                                      out /* y1 scratch */, finals);
    // Layer 1
    gemm_xp<<<ggrid, 256, 0, stream>>>(out, W_ih + Hx * Hx, b_ih + Hx, xp);
    rnn_scan<<<Bx, 1024, 0, stream>>>(xp, h0 + (size_t)Bx * Hx,
                                      W_hh + Hx * Hx, b_hh + Hx,
                                      out, finals + (size_t)Bx * Hx);
}

// Round 9
// 2668.740 us; speedup vs baseline: 1.3008x; 1.3008x over previous
//
#include <hip/hip_runtime.h>
#include <cstddef>

// Problem dims (fixed by the reference)
#define Bx 32
#define Sx 2048
#define Hx 256
#define Lx 2

// ------------------------------------------------------------------
// GEMM: C[m,n] = sum_k A[m,k] * W[n,k] + bias[n]   (unchanged; ~185 us)
// ------------------------------------------------------------------
#define GBM 64
#define GBN 64
#define GBK 32

__global__ __launch_bounds__(256) void gemm_xp(
    const float* __restrict__ A,
    const float* __restrict__ W,
    const float* __restrict__ bias,
    float* __restrict__ C)
{
    __shared__ float As[GBK][GBM + 1];
    __shared__ float Ws[GBK][GBN + 1];

    const int tid = threadIdx.x;
    const int tx  = tid & 15;
    const int ty  = tid >> 4;
    const int m0  = blockIdx.x * GBM;
    const int n0  = blockIdx.y * GBN;
    const int r   = tid >> 3;
    const int c4  = tid & 7;

    float acc[4][4] = {};

    for (int k0 = 0; k0 < Hx; k0 += GBK) {
        const float4 a0 = *(const float4*)(A + (size_t)(m0 + r)      * Hx + k0 + c4 * 4);
        const float4 a1 = *(const float4*)(A + (size_t)(m0 + r + 32) * Hx + k0 + c4 * 4);
        const float4 w0 = *(const float4*)(W + (size_t)(n0 + r)      * Hx + k0 + c4 * 4);
        const float4 w1 = *(const float4*)(W + (size_t)(n0 + r + 32) * Hx + k0 + c4 * 4);

        __syncthreads();

        As[c4 * 4 + 0][r] = a0.x;  As[c4 * 4 + 1][r] = a0.y;
        As[c4 * 4 + 2][r] = a0.z;  As[c4 * 4 + 3][r] = a0.w;
        As[c4 * 4 + 0][r + 32] = a1.x;  As[c4 * 4 + 1][r + 32] = a1.y;
        As[c4 * 4 + 2][r + 32] = a1.z;  As[c4 * 4 + 3][r + 32] = a1.w;

        Ws[c4 * 4 + 0][r] = w0.x;  Ws[c4 * 4 + 1][r] = w0.y;
        Ws[c4 * 4 + 2][r] = w0.z;  Ws[c4 * 4 + 3][r] = w0.w;
        Ws[c4 * 4 + 0][r + 32] = w1.x;  Ws[c4 * 4 + 1][r + 32] = w1.y;
        Ws[c4 * 4 + 2][r + 32] = w1.z;  Ws[c4 * 4 + 3][r + 32] = w1.w;

        __syncthreads();

        #pragma unroll
        for (int k = 0; k < GBK; ++k) {
            float av[4], wv[4];
            #pragma unroll
            for (int i = 0; i < 4; ++i) av[i] = As[k][ty * 4 + i];
            #pragma unroll
            for (int j = 0; j < 4; ++j) wv[j] = Ws[k][tx * 4 + j];
            #pragma unroll
            for (int i = 0; i < 4; ++i)
                #pragma unroll
                for (int j = 0; j < 4; ++j)
                    acc[i][j] = fmaf(av[i], wv[j], acc[i][j]);
        }
    }

    const float4 bv = *(const float4*)(bias + n0 + tx * 4);
    #pragma unroll
    for (int i = 0; i < 4; ++i) {
        float4 o;
        o.x = acc[i][0] + bv.x;
        o.y = acc[i][1] + bv.y;
        o.z = acc[i][2] + bv.z;
        o.w = acc[i][3] + bv.w;
        *(float4*)(C + (size_t)(m0 + ty * 4 + i) * Hx + n0 + tx * 4) = o;
    }
}

// ------------------------------------------------------------------
// DPP butterfly: reduction entirely on the VALU (no DS pipe).
// ------------------------------------------------------------------
template <int CTRL>
__device__ __forceinline__ float dpp_xadd(float x) {
    int xi = __builtin_bit_cast(int, x);
    int yi = __builtin_amdgcn_update_dpp(0, xi, CTRL, 0xF, 0xF, true);
    return x + __builtin_bit_cast(float, yi);
}
__device__ __forceinline__ float red8(float s) {
    s = dpp_xadd<0xB1>(s);    // + lane^1  (quad_perm [1,0,3,2])
    s = dpp_xadd<0x4E>(s);    // + lane^2  (quad_perm [2,3,0,1])
    s = dpp_xadd<0x128>(s);   // + lane^8  (row_ror:8)
    return s;
}

// Fast tanh: 1 - 2/(1+e^{2x}).  ~5 VALU insts (mul, scale+v_exp, add,
// v_rcp, fma) vs ocml tanhf's ~25-40. Saturates correctly at +-1 for
// large |x| (exp->inf -> rcp->0; exp->0 -> 1-2). Abs err ~1e-7.
__device__ __forceinline__ float fast_tanh(float x) {
    float e = __expf(2.0f * x);
    return 1.0f - 2.0f * __builtin_amdgcn_rcpf(1.0f + e);
}

// One recurrence step vs LDS buffer PH (0/1). foff[] = loop-invariant
// rotated float-offsets into hsf[PH]. Direct shared-array indexing ->
// guaranteed addrspace(3) ds_read_b128 (round-8 suspicion: the old
// `const char* va[]` indirection defeated InferAddressSpaces -> flat
// loads, inflating VALU and bypassing the LDS-conflict counter).
template <int PH>
__device__ __forceinline__ float step_ds(const float (&hsf)[2][Hx],
                                         const float4 (&wq)[4][8],
                                         const int (&foff)[8],
                                         float xv, float bias, int lane)
{
    float4 h4[8];
    #pragma unroll
    for (int j = 0; j < 8; ++j)
        h4[j] = *(const float4*)&hsf[PH][foff[j]];

    float s0 = 0.f, s1 = 0.f, s2 = 0.f, s3 = 0.f;
    #pragma unroll
    for (int j = 0; j < 8; ++j) {
        // component-major: each accumulator's FMAs 4 insts apart
        s0 = fmaf(wq[0][j].x, h4[j].x, s0);
        s1 = fmaf(wq[1][j].x, h4[j].x, s1);
        s2 = fmaf(wq[2][j].x, h4[j].x, s2);
        s3 = fmaf(wq[3][j].x, h4[j].x, s3);
        s0 = fmaf(wq[0][j].y, h4[j].y, s0);
        s1 = fmaf(wq[1][j].y, h4[j].y, s1);
        s2 = fmaf(wq[2][j].y, h4[j].y, s2);
        s3 = fmaf(wq[3][j].y, h4[j].y, s3);
        s0 = fmaf(wq[0][j].z, h4[j].z, s0);
        s1 = fmaf(wq[1][j].z, h4[j].z, s1);
        s2 = fmaf(wq[2][j].z, h4[j].z, s2);
        s3 = fmaf(wq[3][j].z, h4[j].z, s3);
        s0 = fmaf(wq[0][j].w, h4[j].w, s0);
        s1 = fmaf(wq[1][j].w, h4[j].w, s1);
        s2 = fmaf(wq[2][j].w, h4[j].w, s2);
        s3 = fmaf(wq[3][j].w, h4[j].w, s3);
    }

    // VALU-only butterfly over lane bits {0,1,3}
    s0 = red8(s0);  s1 = red8(s1);  s2 = red8(s2);  s3 = red8(s3);

    // static select of this lane's output sum (index = lane&3)
    const float sa  = (lane & 1) ? s1 : s0;
    const float sc  = (lane & 1) ? s3 : s2;
    const float sel = (lane & 2) ? sc : sa;

    return fast_tanh(xv + sel + bias);
}

// ------------------------------------------------------------------
// Recurrence v7: one WG per batch, 512 threads (8 waves), 1 barrier/step.
// Proven layout: k-slice ks on lane bits {0,1,3}, output-quad on bits
// {2,4,5}; ks-rotated reads; DPP reduce; 2x-unrolled double buffer.
// Round-9 changes: (1) pure shared-array indexing (force ds_read_b128),
// (2) NO register pins (if weights live in AGPRs the unified-file VALU
// sources them directly; pins only added copy pairs), (3) fast_tanh.
// ------------------------------------------------------------------
__global__ __launch_bounds__(512)
__attribute__((amdgpu_waves_per_eu(2, 2)))
void rnn_scan(
    const float* __restrict__ xp,    // [B,S,H] precomputed x@W_ih^T + b_ih
    const float* __restrict__ h0l,   // [B,H]
    const float* __restrict__ Whh,   // [H,H]
    const float* __restrict__ bhh,   // [H]
    float* __restrict__ y,           // [B,S,H]
    float* __restrict__ hfin)        // [B,H]
{
    const int b    = blockIdx.x;
    const int t    = threadIdx.x;
    const int lane = t & 63;
    const int wid  = t >> 6;                               // wave id 0..7
    const int ks   = (lane & 3) | ((lane >> 1) & 4);       // k-slice: bits {0,1,3}
    const int gw   = ((lane >> 2) & 1) | ((lane >> 3) & 6);// group-in-wave: bits {2,4,5}
    const int g    = wid * 8 + gw;                         // output quad 0..63
    const int out  = g * 4 + (lane & 3);                   // output this lane finalizes
    const bool writer = (lane & 8) == 0;                   // ks < 4

    // Weights: wq[o][j] = Whh[g*4+o][ks*32 + ((j+ks)&7)*4 .. +3]
    // (pre-rotated to pair with the rotated LDS offsets below).
    float4 wq[4][8];
    #pragma unroll
    for (int o = 0; o < 4; ++o) {
        const float* wrow = Whh + (size_t)(g * 4 + o) * Hx + ks * 32;
        #pragma unroll
        for (int j = 0; j < 8; ++j)
            wq[o][j] = *(const float4*)(wrow + ((j + ks) & 7) * 4);
    }

    __shared__ float hsf[2][Hx];               // buf1 = buf0 + 1024 bytes
    if (t < Hx) hsf[0][t] = h0l[(size_t)b * Hx + t];
    const float bias = bhh[out];
    __syncthreads();

    // Loop-invariant rotated float-offsets into a buffer (8 ints).
    int foff[8];
    #pragma unroll
    for (int j = 0; j < 8; ++j)
        foff[j] = ks * 32 + ((j + ks) & 7) * 4;

    const float* xpb = xp + (size_t)b * Sx * Hx;
    float*       yb  = y  + (size_t)b * Sx * Hx;

    // 2-deep xp prefetch
    float xv_n1 = xpb[out];
    float xv_n2 = xpb[(size_t)Hx + out];
    float hnew  = 0.0f;

    for (int s = 0; s < Sx; s += 2) {
        // ---- phase 0: read buf0, write buf1 (step s) ----
        {
            const float xv = xv_n1;
            xv_n1 = xv_n2;
            if (s + 2 < Sx) xv_n2 = xpb[(size_t)(s + 2) * Hx + out];

            hnew = step_ds<0>(hsf, wq, foff, xv, bias, lane);
            if (writer) {
                hsf[1][out] = hnew;
                yb[(size_t)s * Hx + out] = hnew;
            }
            __syncthreads();
        }

        // ---- phase 1: read buf1, write buf0 (step s+1) ----
        {
            const float xv = xv_n1;
            xv_n1 = xv_n2;
            if (s + 3 < Sx) xv_n2 = xpb[(size_t)(s + 3) * Hx + out];

            hnew = step_ds<1>(hsf, wq, foff, xv, bias, lane);
            if (writer) {
                hsf[0][out] = hnew;
                yb[(size_t)(s + 1) * Hx + out] = hnew;
            }
            __syncthreads();
        }
    }

    if (writer) hfin[(size_t)b * Hx + out] = hnew;
}

// ------------------------------------------------------------------
// Launch: GEMM(l0) -> scan(l0) -> GEMM(l1) -> scan(l1), stream-ordered.
// ws: xp scratch (64 MB). d_out[0:B*S*H] doubles as y1 scratch before the
// layer-2 scan overwrites it (we fully rewrite d_out every call).
// ------------------------------------------------------------------
extern "C" void kernel_launch(void* const* d_in, const int* in_sizes, int n_in,
                              void* d_out, int out_size, void* d_ws, size_t ws_size,
                              hipStream_t stream) {
    const float* x    = (const float*)d_in[0];   // [B,S,H]
    const float* h0   = (const float*)d_in[1];   // [L,B,H]
    const float* W_ih = (const float*)d_in[2];   // [L,H,H]
    const float* W_hh = (const float*)d_in[3];   // [L,H,H]
    const float* b_ih = (const float*)d_in[4];   // [L,H]
    const float* b_hh = (const float*)d_in[5];   // [L,H]

    float* out    = (float*)d_out;                       // [B,S,H]
    float* finals = out + (size_t)Bx * Sx * Hx;          // [L,B,H]
    float* xp     = (float*)d_ws;                        // [B,S,H] scratch

    const dim3 ggrid(Bx * Sx / GBM, Hx / GBN);           // (1024, 4)

    // Layer 0
    gemm_xp<<<ggrid, 256, 0, stream>>>(x, W_ih, b_ih, xp);
    rnn_scan<<<Bx, 512, 0, stream>>>(xp, h0, W_hh, b_hh,
                                     out /* y1 scratch */, finals);
    // Layer 1
    gemm_xp<<<ggrid, 256, 0, stream>>>(out, W_ih + Hx * Hx, b_ih + Hx, xp);
    rnn_scan<<<Bx, 512, 0, stream>>>(xp, h0 + (size_t)Bx * Hx,
                                     W_hh + Hx * Hx, b_hh + Hx,
                                     out, finals + (size_t)Bx * Hx);
}